// Round 4
// baseline (919.445 us; speedup 1.0000x reference)
//
#include <hip/hip_runtime.h>
#include <hip/hip_cooperative_groups.h>

namespace cg = cooperative_groups;

// ---------------------------------------------------------------------------
// Algebraic collapse: the scan is linear & batch-independent.
//   m_{t+1} = A m_t + beta,  A[(j,e),(i,d)] = gate[i,j]*W[i,j,e,d]
//   out = inp @ Weff^T + beff,  Weff = Wpost * S * Wpre,
//   S = (A^10)[block15, block0],  c = (sum_{k<10} A^k beta)[block15]
// QT [144 x 2048] iterate in split-bf16 (hi+lo), fp32 MFMA accumulate.
// Round 4: coop grid shrunk 512->256 blocks (1/CU, big co-residency headroom);
// launch is pre-checked + error-checked with a deterministic multi-launch
// fallback sharing the same device-function bodies. prep + coop + final = 3
// dispatches on the fast path.
// ---------------------------------------------------------------------------

typedef __bf16 bf16x8 __attribute__((ext_vector_type(8)));
typedef float f32x4 __attribute__((ext_vector_type(4)));

__device__ __forceinline__ unsigned short f2bf(float x) {
  unsigned int u = __float_as_uint(x);
  u += 0x7FFFu + ((u >> 16) & 1u);   // round-to-nearest-even
  return (unsigned short)(u >> 16);
}
__device__ __forceinline__ float bf2f(unsigned short s) {
  return __uint_as_float(((unsigned int)s) << 16);
}
__device__ __forceinline__ bf16x8 ldg8(const unsigned short* p) {
  return __builtin_bit_cast(bf16x8, *(const uint4*)p);
}
__device__ __forceinline__ f32x4 mfma16(bf16x8 a, bf16x8 b, f32x4 c) {
  return __builtin_amdgcn_mfma_f32_16x16x32_bf16(a, b, c, 0, 0, 0);
}

#define ND 2048   // num*dim
#define MT 144    // iterate rows (129 used: 128 propagator + 1 bias; rest 0)
#define KS 4      // split-K chunks (k-chunk = 512)

// ---------------------------------------------------------------------------
// prep: blocks 0..2047 build split-A; 2048..3071 split inp; 3072..3135 build
// Q1 (exact step t=1) directly from W + beta row. All independent.
// ---------------------------------------------------------------------------
__global__ __launch_bounds__(256) void prep_kernel(
    const float* __restrict__ W, const float* __restrict__ life,
    const float* __restrict__ inp, const float* __restrict__ bl,
    unsigned short* __restrict__ Ahi, unsigned short* __restrict__ Alo,
    unsigned short* __restrict__ Ihi, unsigned short* __restrict__ Ilo,
    unsigned short* __restrict__ Qhi, unsigned short* __restrict__ Qlo,
    float* __restrict__ beta) {
  const int b = blockIdx.x, t = threadIdx.x;
  if (b < 2048) {
    long base = ((long)b * 256 + t) * 8;
    int n = (int)(base >> 11), k = (int)(base & 2047);
    int j = n >> 7, e = n & 127, i = k >> 7, d0 = k & 127;
    float gv = life[i * 16 + j];
    float gate = gv > 0.f ? gv : 0.f;
    const float* src = W + ((i * 16 + j) * 16384 + e * 128 + d0);
    float4 a = *(const float4*)src, b4 = *(const float4*)(src + 4);
    float vals[8] = {a.x, a.y, a.z, a.w, b4.x, b4.y, b4.z, b4.w};
    union { unsigned short u[8]; uint4 v; } ph, pl;
#pragma unroll
    for (int x = 0; x < 8; ++x) {
      float v = gate * vals[x];
      unsigned short h = f2bf(v);
      ph.u[x] = h;
      pl.u[x] = f2bf(v - bf2f(h));
    }
    *(uint4*)(Ahi + base) = ph.v;
    *(uint4*)(Alo + base) = pl.v;
  } else if (b < 3072) {
    long base = ((long)(b - 2048) * 256 + t) * 8;
    float4 a = *(const float4*)(inp + base), b4 = *(const float4*)(inp + base + 4);
    float vals[8] = {a.x, a.y, a.z, a.w, b4.x, b4.y, b4.z, b4.w};
    union { unsigned short u[8]; uint4 v; } ph, pl;
#pragma unroll
    for (int x = 0; x < 8; ++x) {
      unsigned short h = f2bf(vals[x]);
      ph.u[x] = h;
      pl.u[x] = f2bf(vals[x] - bf2f(h));
    }
    *(uint4*)(Ihi + base) = ph.v;
    *(uint4*)(Ilo + base) = pl.v;
  } else {
    // Q1[c][n] = gate[0,j]*W[0,j,e,c] (exact t=1), c<128; row 128 = beta.
    const int nb = b - 3072;                 // n-range [nb*32, nb*32+32)
    {
      int n = nb * 32 + (t >> 3);
      int c0 = (t & 7) * 16;
      int j = n >> 7, e = n & 127;
      float gv = life[j];
      float gate = gv > 0.f ? gv : 0.f;
      const float* src = W + (j * 16384 + e * 128 + c0);
      float4 w0 = *(const float4*)src, w1 = *(const float4*)(src + 4);
      float4 w2 = *(const float4*)(src + 8), w3 = *(const float4*)(src + 12);
      float vals[16] = {w0.x, w0.y, w0.z, w0.w, w1.x, w1.y, w1.z, w1.w,
                        w2.x, w2.y, w2.z, w2.w, w3.x, w3.y, w3.z, w3.w};
#pragma unroll
      for (int x = 0; x < 16; ++x) {
        float v = gate * vals[x];
        unsigned short h = f2bf(v);
        Qhi[(c0 + x) * ND + n] = h;
        Qlo[(c0 + x) * ND + n] = f2bf(v - bf2f(h));
      }
    }
    if (t < 32) {
      int n = nb * 32 + t;
      int j = n >> 7, e = n & 127;
      float s = 0.f;
#pragma unroll
      for (int i = 0; i < 16; ++i) {
        float gv = life[i * 16 + j];
        float g = gv > 0.f ? gv : 0.f;
        s += g * bl[(i * 16 + j) * 128 + e];
      }
      beta[n] = s;
      unsigned short h = f2bf(s);
      Qhi[128 * ND + n] = h;
      Qlo[128 * ND + n] = f2bf(s - bf2f(h));
    }
    for (int idx = t; idx < 480; idx += 256) {
      int r = 129 + (idx >> 5), n = nb * 32 + (idx & 31);
      Qhi[r * ND + n] = 0;
      Qlo[r * ND + n] = 0;
    }
  }
}

// ---------------------------------------------------------------------------
// Shared phase bodies (used by coop kernel AND fallback kernels)
// ---------------------------------------------------------------------------

// GEMM phase: P[kc][c][n] = sum_{k in chunk} QT[c,k]*A[n,k]. One block covers
// n-tile nb (32 wide), k-chunk kc (512). 3 waves; wave wv owns m [wv*48,+48).
__device__ __forceinline__ void gemm_phase(
    const unsigned short* __restrict__ Ahi, const unsigned short* __restrict__ Alo,
    const unsigned short* __restrict__ qh, const unsigned short* __restrict__ ql,
    float* __restrict__ P, int nb, int kc, int t) {
  const int wv = t >> 6, lane = t & 63;
  const int r16 = lane & 15, q = lane >> 4;
  const int kbase = kc * 512 + q * 8;
  const int n0 = nb * 32;
  const unsigned short* pB0h = Ahi + (n0 + r16) * ND + kbase;
  const unsigned short* pB0l = Alo + (n0 + r16) * ND + kbase;
  const int m0 = wv * 48 + r16;
  const unsigned short* pA0h = qh + m0 * ND + kbase;
  const unsigned short* pA0l = ql + m0 * ND + kbase;

  f32x4 acc[3][2];
#pragma unroll
  for (int mt = 0; mt < 3; ++mt)
#pragma unroll
    for (int nt = 0; nt < 2; ++nt) acc[mt][nt] = (f32x4){0.f, 0.f, 0.f, 0.f};

#pragma unroll 2
  for (int it = 0; it < 16; ++it) {
    const int ko = it * 32;
    bf16x8 b0h = ldg8(pB0h + ko), b0l = ldg8(pB0l + ko);
    bf16x8 b1h = ldg8(pB0h + 16 * ND + ko), b1l = ldg8(pB0l + 16 * ND + ko);
    bf16x8 a0h = ldg8(pA0h + ko), a0l = ldg8(pA0l + ko);
    bf16x8 a1h = ldg8(pA0h + 16 * ND + ko), a1l = ldg8(pA0l + 16 * ND + ko);
    bf16x8 a2h = ldg8(pA0h + 32 * ND + ko), a2l = ldg8(pA0l + 32 * ND + ko);

    acc[0][0] = mfma16(a0h, b0h, acc[0][0]);
    acc[0][0] = mfma16(a0l, b0h, acc[0][0]);
    acc[0][0] = mfma16(a0h, b0l, acc[0][0]);
    acc[1][0] = mfma16(a1h, b0h, acc[1][0]);
    acc[1][0] = mfma16(a1l, b0h, acc[1][0]);
    acc[1][0] = mfma16(a1h, b0l, acc[1][0]);
    acc[2][0] = mfma16(a2h, b0h, acc[2][0]);
    acc[2][0] = mfma16(a2l, b0h, acc[2][0]);
    acc[2][0] = mfma16(a2h, b0l, acc[2][0]);
    acc[0][1] = mfma16(a0h, b1h, acc[0][1]);
    acc[0][1] = mfma16(a0l, b1h, acc[0][1]);
    acc[0][1] = mfma16(a0h, b1l, acc[0][1]);
    acc[1][1] = mfma16(a1h, b1h, acc[1][1]);
    acc[1][1] = mfma16(a1l, b1h, acc[1][1]);
    acc[1][1] = mfma16(a1h, b1l, acc[1][1]);
    acc[2][1] = mfma16(a2h, b1h, acc[2][1]);
    acc[2][1] = mfma16(a2l, b1h, acc[2][1]);
    acc[2][1] = mfma16(a2h, b1l, acc[2][1]);
  }

  float* Pk = P + kc * (MT * ND);
#pragma unroll
  for (int mt = 0; mt < 3; ++mt)
#pragma unroll
    for (int nt = 0; nt < 2; ++nt) {
      int mbase = wv * 48 + mt * 16 + q * 4;
      int n = n0 + nt * 16 + r16;
#pragma unroll
      for (int r = 0; r < 4; ++r)
        Pk[(mbase + r) * ND + n] = acc[mt][nt][r];
    }
}

// reduce: x indexes float4 over MT x ND (x in [0, 73728))
__device__ __forceinline__ void reduce_elem(
    const float* __restrict__ P, const float* __restrict__ beta,
    unsigned short* __restrict__ oh, unsigned short* __restrict__ ol, int x) {
  int m = x >> 9, col = (x & 511) * 4;
  int idx = m * ND + col;
  float4 s = *(const float4*)(P + idx);
#pragma unroll
  for (int kcc = 1; kcc < KS; ++kcc) {
    float4 sp = *(const float4*)(P + kcc * (MT * ND) + idx);
    s.x += sp.x; s.y += sp.y; s.z += sp.z; s.w += sp.w;
  }
  if (m == 128) {
    float4 b4 = *(const float4*)(beta + col);
    s.x += b4.x; s.y += b4.y; s.z += b4.z; s.w += b4.w;
  }
  float vv[4] = {s.x, s.y, s.z, s.w};
  union { unsigned short u[4]; uint2 d; } h, l;
#pragma unroll
  for (int i = 0; i < 4; ++i) {
    unsigned short hh = f2bf(vv[i]);
    h.u[i] = hh;
    l.u[i] = f2bf(vv[i] - bf2f(hh));
  }
  *(uint2*)(oh + idx) = h.d;
  *(uint2*)(ol + idx) = l.d;
}

// small-step reduce -> S (fp32) + cvec (x in [0, 16512))
__device__ __forceinline__ void sred_elem(
    const float* __restrict__ P, const float* __restrict__ beta,
    float* __restrict__ S, float* __restrict__ cvec, int x) {
  if (x < 16384) {
    int d = x >> 7, e = x & 127;
    float s = 0.f;
#pragma unroll
    for (int kcc = 0; kcc < KS; ++kcc)
      s += P[kcc * (MT * ND) + d * ND + 1920 + e];
    S[e * 128 + d] = s;
  } else {
    int e = x - 16384;
    float s = beta[1920 + e];
#pragma unroll
    for (int kcc = 0; kcc < KS; ++kcc)
      s += P[kcc * (MT * ND) + 128 * ND + 1920 + e];
    cvec[e] = s;
  }
}

// tail1: T1 = S*Wpre; g = S.bpre + cvec (x in [0, 65664))
__device__ __forceinline__ void tail1_elem(
    const float* __restrict__ S, const float* __restrict__ Wpre,
    const float* __restrict__ bpre, const float* __restrict__ cvec,
    float* __restrict__ T1, float* __restrict__ g, int x) {
  if (x < 65536) {
    int e = x >> 9, ic = x & 511;
    float s = 0.f;
    for (int d = 0; d < 128; ++d) s += S[e * 128 + d] * Wpre[d * 512 + ic];
    T1[x] = s;
  } else {
    int e = x - 65536;
    float s = cvec[e];
    for (int d = 0; d < 128; ++d) s += S[e * 128 + d] * bpre[d];
    g[e] = s;
  }
}

// tail2: Weff split + beff (x in [0, 262656))
__device__ __forceinline__ void tail2_elem(
    const float* __restrict__ Wpost, const float* __restrict__ T1,
    const float* __restrict__ g, const float* __restrict__ bpost,
    unsigned short* __restrict__ Whi, unsigned short* __restrict__ Wlo,
    float* __restrict__ beff, int x) {
  if (x < 262144) {
    int o = x >> 9, ic = x & 511;
    float s = 0.f;
    for (int e = 0; e < 128; ++e) s += Wpost[o * 128 + e] * T1[e * 512 + ic];
    unsigned short h = f2bf(s);
    Whi[x] = h;
    Wlo[x] = f2bf(s - bf2f(h));
  } else {
    int o = x - 262144;
    float s = bpost[o];
    for (int e = 0; e < 128; ++e) s += Wpost[o * 128 + e] * g[e];
    beff[o] = s;
  }
}

// ---------------------------------------------------------------------------
// Cooperative kernel: 256 blocks (64 nb x 4 kc) x 192 threads (1 block/CU).
// ---------------------------------------------------------------------------
struct CoopArgs {
  const unsigned short *Ahi, *Alo;
  unsigned short *QAhi, *QAlo, *QBhi, *QBlo;
  float* P;
  const float* beta;
  float *S, *cvec, *g, *T1;
  const float *Wpre, *bpre, *Wpost, *bpost;
  unsigned short *Whi, *Wlo;
  float* beff;
};

#define GT (256 * 192)   // coop grid threads = 49152

__global__ __launch_bounds__(192, 2) void coop_kernel(CoopArgs a) {
  cg::grid_group grid = cg::this_grid();
  const int t = threadIdx.x;
  const int b = blockIdx.x;
  const int nb = b & 63, kc = b >> 6;
  const int tid = b * 192 + t;

  const unsigned short* qh = a.QAhi;
  const unsigned short* ql = a.QAlo;
  unsigned short* oh = a.QBhi;
  unsigned short* ol = a.QBlo;

  for (int step = 0; step < 9; ++step) {
    const bool small = (step == 8);
    if (!small || nb >= 60)
      gemm_phase(a.Ahi, a.Alo, qh, ql, a.P, nb, kc, t);
    grid.sync();

    if (!small) {
      for (int x = tid; x < 73728; x += GT)
        reduce_elem(a.P, a.beta, oh, ol, x);
      grid.sync();
      const unsigned short* th = qh; qh = oh; oh = (unsigned short*)th;
      const unsigned short* tl = ql; ql = ol; ol = (unsigned short*)tl;
    } else {
      for (int x = tid; x < 16512; x += GT)
        sred_elem(a.P, a.beta, a.S, a.cvec, x);
      grid.sync();
    }
  }

  for (int x = tid; x < 65664; x += GT)
    tail1_elem(a.S, a.Wpre, a.bpre, a.cvec, a.T1, a.g, x);
  grid.sync();
  for (int x = tid; x < 262656; x += GT)
    tail2_elem(a.Wpost, a.T1, a.g, a.bpost, a.Whi, a.Wlo, a.beff, x);
}

// ---------------------------------------------------------------------------
// Fallback kernels (same bodies, separate launches) — used only if the
// cooperative launch is unsupported or fails.
// ---------------------------------------------------------------------------
__global__ __launch_bounds__(192) void step_fb(
    const unsigned short* __restrict__ Ahi, const unsigned short* __restrict__ Alo,
    const unsigned short* __restrict__ qh, const unsigned short* __restrict__ ql,
    float* __restrict__ P, int nb_off) {
  gemm_phase(Ahi, Alo, qh, ql, P, blockIdx.x + nb_off, blockIdx.y, threadIdx.x);
}
__global__ void reduce_fb(const float* __restrict__ P, const float* __restrict__ beta,
                          unsigned short* __restrict__ oh, unsigned short* __restrict__ ol) {
  int x = blockIdx.x * 256 + threadIdx.x;   // 288*256 = 73728 exact
  reduce_elem(P, beta, oh, ol, x);
}
__global__ void sred_fb(const float* __restrict__ P, const float* __restrict__ beta,
                        float* __restrict__ S, float* __restrict__ cvec) {
  int x = blockIdx.x * 256 + threadIdx.x;
  if (x < 16512) sred_elem(P, beta, S, cvec, x);
}
__global__ void tail1_fb(const float* __restrict__ S, const float* __restrict__ Wpre,
                         const float* __restrict__ bpre, const float* __restrict__ cvec,
                         float* __restrict__ T1, float* __restrict__ g) {
  int x = blockIdx.x * 256 + threadIdx.x;
  if (x < 65664) tail1_elem(S, Wpre, bpre, cvec, T1, g, x);
}
__global__ void tail2_fb(const float* __restrict__ Wpost, const float* __restrict__ T1,
                         const float* __restrict__ g, const float* __restrict__ bpost,
                         unsigned short* __restrict__ Whi, unsigned short* __restrict__ Wlo,
                         float* __restrict__ beff) {
  int x = blockIdx.x * 256 + threadIdx.x;
  if (x < 262656) tail2_elem(Wpost, T1, g, bpost, Whi, Wlo, beff, x);
}

// ---------------------------------------------------------------------------
// out[4096,512] = inp @ Weff^T + beff. M=4096,N=512,K=512, split bf16.
// ---------------------------------------------------------------------------
__global__ __launch_bounds__(256) void final_gemm(
    const unsigned short* __restrict__ Ihi, const unsigned short* __restrict__ Ilo,
    const unsigned short* __restrict__ Whi, const unsigned short* __restrict__ Wlo,
    const float* __restrict__ beff, float* __restrict__ out) {
  __shared__ __align__(16) unsigned short Is_hi[64][40], Is_lo[64][40];
  __shared__ __align__(16) unsigned short Ws_hi[128][40], Ws_lo[128][40];
  const int t = threadIdx.x;
  const int mb = blockIdx.x, nb = blockIdx.y;
  const int w = t >> 6, lane = t & 63;
  const int r16 = lane & 15, q = lane >> 4;

  f32x4 acc[4][2];
#pragma unroll
  for (int x = 0; x < 4; ++x)
#pragma unroll
    for (int y = 0; y < 2; ++y) acc[x][y] = (f32x4){0.f, 0.f, 0.f, 0.f};

  for (int kc = 0; kc < 16; ++kc) {
    const int k0 = kc * 32;
#pragma unroll
    for (int rpt = 0; rpt < 6; ++rpt) {
      int slot = t + rpt * 256;
      if (slot < 512) {
        int arr = slot >> 8, s = slot & 255;
        int row = s >> 2, off = (s & 3) * 8;
        const unsigned short* src = arr ? Ilo : Ihi;
        unsigned short* dst = arr ? &Is_lo[row][off] : &Is_hi[row][off];
        *(uint4*)dst = *(const uint4*)(src + (mb * 64 + row) * 512 + k0 + off);
      } else {
        int s = slot - 512;
        int arr = s >> 9, s2 = s & 511;
        int row = s2 >> 2, off = (s2 & 3) * 8;
        const unsigned short* src = arr ? Wlo : Whi;
        unsigned short* dst = arr ? &Ws_lo[row][off] : &Ws_hi[row][off];
        *(uint4*)dst = *(const uint4*)(src + (nb * 128 + row) * 512 + k0 + off);
      }
    }
    __syncthreads();

    bf16x8 bh0 = __builtin_bit_cast(bf16x8, *(const uint4*)&Ws_hi[w * 32 + r16][q * 8]);
    bf16x8 bl0 = __builtin_bit_cast(bf16x8, *(const uint4*)&Ws_lo[w * 32 + r16][q * 8]);
    bf16x8 bh1 = __builtin_bit_cast(bf16x8, *(const uint4*)&Ws_hi[w * 32 + 16 + r16][q * 8]);
    bf16x8 bl1 = __builtin_bit_cast(bf16x8, *(const uint4*)&Ws_lo[w * 32 + 16 + r16][q * 8]);
#pragma unroll
    for (int mt = 0; mt < 4; ++mt) {
      bf16x8 ah = __builtin_bit_cast(bf16x8, *(const uint4*)&Is_hi[mt * 16 + r16][q * 8]);
      bf16x8 al = __builtin_bit_cast(bf16x8, *(const uint4*)&Is_lo[mt * 16 + r16][q * 8]);
      acc[mt][0] = mfma16(ah, bh0, acc[mt][0]);
      acc[mt][0] = mfma16(al, bh0, acc[mt][0]);
      acc[mt][0] = mfma16(ah, bl0, acc[mt][0]);
      acc[mt][1] = mfma16(ah, bh1, acc[mt][1]);
      acc[mt][1] = mfma16(al, bh1, acc[mt][1]);
      acc[mt][1] = mfma16(ah, bl1, acc[mt][1]);
    }
    __syncthreads();
  }

#pragma unroll
  for (int mt = 0; mt < 4; ++mt)
#pragma unroll
    for (int nt = 0; nt < 2; ++nt) {
      int n = nb * 128 + w * 32 + nt * 16 + r16;
      float bv = beff[n];
#pragma unroll
      for (int r = 0; r < 4; ++r) {
        int m = mb * 64 + mt * 16 + q * 4 + r;
        out[m * 512 + n] = acc[mt][nt][r] + bv;
      }
    }
}

extern "C" void kernel_launch(void* const* d_in, const int* in_sizes, int n_in,
                              void* d_out, int out_size, void* d_ws, size_t ws_size,
                              hipStream_t stream) {
  const float* inp   = (const float*)d_in[0];
  const float* Wpre  = (const float*)d_in[1];
  const float* bpre  = (const float*)d_in[2];
  const float* W     = (const float*)d_in[3];
  const float* bl    = (const float*)d_in[4];
  const float* life  = (const float*)d_in[5];
  const float* Wpost = (const float*)d_in[6];
  const float* bpost = (const float*)d_in[7];
  float* out = (float*)d_out;

  char* p = (char*)d_ws;
  auto alloc = [&](size_t bytes) {
    char* r = p;
    p += (bytes + 255) & ~(size_t)255;
    return r;
  };
  unsigned short* Ahi  = (unsigned short*)alloc((size_t)ND * ND * 2);
  unsigned short* Alo  = (unsigned short*)alloc((size_t)ND * ND * 2);
  unsigned short* QAhi = (unsigned short*)alloc((size_t)MT * ND * 2);
  unsigned short* QAlo = (unsigned short*)alloc((size_t)MT * ND * 2);
  unsigned short* QBhi = (unsigned short*)alloc((size_t)MT * ND * 2);
  unsigned short* QBlo = (unsigned short*)alloc((size_t)MT * ND * 2);
  float* P    = (float*)alloc((size_t)KS * MT * ND * 4);
  float* beta = (float*)alloc(ND * 4);
  float* S    = (float*)alloc(128 * 128 * 4);
  float* cvec = (float*)alloc(128 * 4);
  float* g    = (float*)alloc(128 * 4);
  float* T1   = (float*)alloc(128 * 512 * 4);
  unsigned short* Whi = (unsigned short*)alloc(512 * 512 * 2);
  unsigned short* Wlo = (unsigned short*)alloc(512 * 512 * 2);
  float* beff = (float*)alloc(512 * 4);
  unsigned short* Ihi = (unsigned short*)alloc((size_t)4096 * 512 * 2);
  unsigned short* Ilo = (unsigned short*)alloc((size_t)4096 * 512 * 2);

  prep_kernel<<<3136, 256, 0, stream>>>(W, life, inp, bl, Ahi, Alo, Ihi, Ilo,
                                        QAhi, QAlo, beta);

  CoopArgs args;
  args.Ahi = Ahi; args.Alo = Alo;
  args.QAhi = QAhi; args.QAlo = QAlo; args.QBhi = QBhi; args.QBlo = QBlo;
  args.P = P; args.beta = beta;
  args.S = S; args.cvec = cvec; args.g = g; args.T1 = T1;
  args.Wpre = Wpre; args.bpre = bpre; args.Wpost = Wpost; args.bpost = bpost;
  args.Whi = Whi; args.Wlo = Wlo; args.beff = beff;

  // Deterministic, capture-safe capability probe (same answer every call).
  int dev = 0;
  (void)hipGetDevice(&dev);
  int coopAttr = 0;
  (void)hipDeviceGetAttribute(&coopAttr, hipDeviceAttributeCooperativeLaunch, dev);
  int maxBlk = 0;
  (void)hipOccupancyMaxActiveBlocksPerMultiprocessor(&maxBlk, (const void*)coop_kernel,
                                                     192, 0);
  hipError_t ce = hipErrorUnknown;
  if (coopAttr && maxBlk >= 1) {
    void* kp[] = {&args};
    ce = hipLaunchCooperativeKernel((void*)coop_kernel, dim3(256), dim3(192), kp,
                                    0, stream);
  }
  if (ce != hipSuccess) {
    // Fallback: identical phases as separate launches (proven round-2 path).
    const unsigned short *qh = QAhi, *ql = QAlo;
    unsigned short *oh = QBhi, *ol = QBlo;
    for (int i = 0; i < 8; ++i) {
      step_fb<<<dim3(64, KS), 192, 0, stream>>>(Ahi, Alo, qh, ql, P, 0);
      reduce_fb<<<288, 256, 0, stream>>>(P, beta, oh, ol);
      const unsigned short* th = qh; qh = oh; oh = (unsigned short*)th;
      const unsigned short* tl = ql; ql = ol; ol = (unsigned short*)tl;
    }
    step_fb<<<dim3(4, KS), 192, 0, stream>>>(Ahi, Alo, qh, ql, P, 60);
    sred_fb<<<65, 256, 0, stream>>>(P, beta, S, cvec);
    tail1_fb<<<257, 256, 0, stream>>>(S, Wpre, bpre, cvec, T1, g);
    tail2_fb<<<1026, 256, 0, stream>>>(Wpost, T1, g, bpost, Whi, Wlo, beff);
  }

  final_gemm<<<dim3(64, 4), 256, 0, stream>>>(Ihi, Ilo, Whi, Wlo, beff, out);
}

// Round 5
// 591.997 us; speedup vs baseline: 1.5531x; 1.5531x over previous
//
#include <hip/hip_runtime.h>

// ---------------------------------------------------------------------------
// Algebraic collapse: the scan is linear & batch-independent.
//   m_{t+1} = A m_t + beta,  A[(j,e),(i,d)] = gate[i,j]*W[i,j,e,d]
//   out = inp @ Weff^T + beff,  Weff = Wpost * S * Wpre,
//   S = (A^10)[block15, block0],  c = (sum_{k<10} A^k beta)[block15]
// QT [144 x 2048] iterate in split-bf16 (hi+lo), fp32 MFMA accumulate.
// Round 5: grid.sync measured ~35 us on gfx950 (cross-XCD L2 flush) -> back
// to multi-launch, but full-K step kernels (no split-K, no reduce kernels,
// fused beta+split epilogue), step-10 writes S/cvec directly, tail fused to
// one kernel with LDS-only T1. 12 dispatches total.
// ---------------------------------------------------------------------------

typedef __bf16 bf16x8 __attribute__((ext_vector_type(8)));
typedef float f32x4 __attribute__((ext_vector_type(4)));

__device__ __forceinline__ unsigned short f2bf(float x) {
  unsigned int u = __float_as_uint(x);
  u += 0x7FFFu + ((u >> 16) & 1u);   // round-to-nearest-even
  return (unsigned short)(u >> 16);
}
__device__ __forceinline__ float bf2f(unsigned short s) {
  return __uint_as_float(((unsigned int)s) << 16);
}
__device__ __forceinline__ bf16x8 ldg8(const unsigned short* p) {
  return __builtin_bit_cast(bf16x8, *(const uint4*)p);
}
__device__ __forceinline__ f32x4 mfma16(bf16x8 a, bf16x8 b, f32x4 c) {
  return __builtin_amdgcn_mfma_f32_16x16x32_bf16(a, b, c, 0, 0, 0);
}

#define ND 2048   // num*dim
#define MT 144    // iterate rows (129 used: 128 propagator + 1 bias; rest 0)

// ---------------------------------------------------------------------------
// prep: blocks 0..2047 build split-A; 2048..3071 split inp; 3072..3135 build
// Q1 (exact step t=1) directly from W + beta row. All independent.
// ---------------------------------------------------------------------------
__global__ __launch_bounds__(256) void prep_kernel(
    const float* __restrict__ W, const float* __restrict__ life,
    const float* __restrict__ inp, const float* __restrict__ bl,
    unsigned short* __restrict__ Ahi, unsigned short* __restrict__ Alo,
    unsigned short* __restrict__ Ihi, unsigned short* __restrict__ Ilo,
    unsigned short* __restrict__ Qhi, unsigned short* __restrict__ Qlo,
    float* __restrict__ beta) {
  const int b = blockIdx.x, t = threadIdx.x;
  if (b < 2048) {
    long base = ((long)b * 256 + t) * 8;
    int n = (int)(base >> 11), k = (int)(base & 2047);
    int j = n >> 7, e = n & 127, i = k >> 7, d0 = k & 127;
    float gv = life[i * 16 + j];
    float gate = gv > 0.f ? gv : 0.f;
    const float* src = W + ((i * 16 + j) * 16384 + e * 128 + d0);
    float4 a = *(const float4*)src, b4 = *(const float4*)(src + 4);
    float vals[8] = {a.x, a.y, a.z, a.w, b4.x, b4.y, b4.z, b4.w};
    union { unsigned short u[8]; uint4 v; } ph, pl;
#pragma unroll
    for (int x = 0; x < 8; ++x) {
      float v = gate * vals[x];
      unsigned short h = f2bf(v);
      ph.u[x] = h;
      pl.u[x] = f2bf(v - bf2f(h));
    }
    *(uint4*)(Ahi + base) = ph.v;
    *(uint4*)(Alo + base) = pl.v;
  } else if (b < 3072) {
    long base = ((long)(b - 2048) * 256 + t) * 8;
    float4 a = *(const float4*)(inp + base), b4 = *(const float4*)(inp + base + 4);
    float vals[8] = {a.x, a.y, a.z, a.w, b4.x, b4.y, b4.z, b4.w};
    union { unsigned short u[8]; uint4 v; } ph, pl;
#pragma unroll
    for (int x = 0; x < 8; ++x) {
      unsigned short h = f2bf(vals[x]);
      ph.u[x] = h;
      pl.u[x] = f2bf(vals[x] - bf2f(h));
    }
    *(uint4*)(Ihi + base) = ph.v;
    *(uint4*)(Ilo + base) = pl.v;
  } else {
    // Q1[c][n] = gate[0,j]*W[0,j,e,c] (exact t=1), c<128; row 128 = beta.
    const int nb = b - 3072;                 // n-range [nb*32, nb*32+32)
    {
      int n = nb * 32 + (t >> 3);
      int c0 = (t & 7) * 16;
      int j = n >> 7, e = n & 127;
      float gv = life[j];
      float gate = gv > 0.f ? gv : 0.f;
      const float* src = W + (j * 16384 + e * 128 + c0);
      float4 w0 = *(const float4*)src, w1 = *(const float4*)(src + 4);
      float4 w2 = *(const float4*)(src + 8), w3 = *(const float4*)(src + 12);
      float vals[16] = {w0.x, w0.y, w0.z, w0.w, w1.x, w1.y, w1.z, w1.w,
                        w2.x, w2.y, w2.z, w2.w, w3.x, w3.y, w3.z, w3.w};
#pragma unroll
      for (int x = 0; x < 16; ++x) {
        float v = gate * vals[x];
        unsigned short h = f2bf(v);
        Qhi[(c0 + x) * ND + n] = h;
        Qlo[(c0 + x) * ND + n] = f2bf(v - bf2f(h));
      }
    }
    if (t < 32) {
      int n = nb * 32 + t;
      int j = n >> 7, e = n & 127;
      float s = 0.f;
#pragma unroll
      for (int i = 0; i < 16; ++i) {
        float gv = life[i * 16 + j];
        float g = gv > 0.f ? gv : 0.f;
        s += g * bl[(i * 16 + j) * 128 + e];
      }
      beta[n] = s;
      unsigned short h = f2bf(s);
      Qhi[128 * ND + n] = h;
      Qlo[128 * ND + n] = f2bf(s - bf2f(h));
    }
    for (int idx = t; idx < 480; idx += 256) {
      int r = 129 + (idx >> 5), n = nb * 32 + (idx & 31);
      Qhi[r * ND + n] = 0;
      Qlo[r * ND + n] = 0;
    }
  }
}

// ---------------------------------------------------------------------------
// GEMM core for one n-tile of 16, full K=2048, 3 waves x 3 m-tiles.
// acc[mt] = sum_k QT[m,k]*A[n,k] in split-bf16 (3 products), fp32 MFMA.
// ---------------------------------------------------------------------------
__device__ __forceinline__ void step_core(
    const unsigned short* __restrict__ Ahi, const unsigned short* __restrict__ Alo,
    const unsigned short* __restrict__ qh, const unsigned short* __restrict__ ql,
    int nb, int t, f32x4 acc[3]) {
  const int wv = t >> 6, lane = t & 63;
  const int r16 = lane & 15, q = lane >> 4;
  const int n0 = nb * 16;
  const int kbase = q * 8;
  const unsigned short* pBh = Ahi + (n0 + r16) * ND + kbase;
  const unsigned short* pBl = Alo + (n0 + r16) * ND + kbase;
  const int m0 = wv * 48 + r16;
  const unsigned short* pAh = qh + m0 * ND + kbase;
  const unsigned short* pAl = ql + m0 * ND + kbase;

  acc[0] = acc[1] = acc[2] = (f32x4){0.f, 0.f, 0.f, 0.f};

#pragma unroll 4
  for (int it = 0; it < 64; ++it) {
    const int ko = it * 32;
    bf16x8 bh = ldg8(pBh + ko), bl = ldg8(pBl + ko);
    bf16x8 a0h = ldg8(pAh + ko), a0l = ldg8(pAl + ko);
    bf16x8 a1h = ldg8(pAh + 16 * ND + ko), a1l = ldg8(pAl + 16 * ND + ko);
    bf16x8 a2h = ldg8(pAh + 32 * ND + ko), a2l = ldg8(pAl + 32 * ND + ko);

    acc[0] = mfma16(a0h, bh, acc[0]);
    acc[0] = mfma16(a0l, bh, acc[0]);
    acc[0] = mfma16(a0h, bl, acc[0]);
    acc[1] = mfma16(a1h, bh, acc[1]);
    acc[1] = mfma16(a1l, bh, acc[1]);
    acc[1] = mfma16(a1h, bl, acc[1]);
    acc[2] = mfma16(a2h, bh, acc[2]);
    acc[2] = mfma16(a2l, bh, acc[2]);
    acc[2] = mfma16(a2h, bl, acc[2]);
  }
}

// Full step: 128 blocks (n-tiles of 16) x 192 thr. Epilogue: +beta on row
// 128, split-bf16 write of Q'. No LDS, no barriers, no split-K.
__global__ __launch_bounds__(192) void step_full(
    const unsigned short* __restrict__ Ahi, const unsigned short* __restrict__ Alo,
    const unsigned short* __restrict__ qh, const unsigned short* __restrict__ ql,
    const float* __restrict__ beta,
    unsigned short* __restrict__ oh, unsigned short* __restrict__ ol) {
  const int t = threadIdx.x;
  f32x4 acc[3];
  step_core(Ahi, Alo, qh, ql, blockIdx.x, t, acc);

  const int wv = t >> 6, lane = t & 63;
  const int r16 = lane & 15, q = lane >> 4;
  const int n = blockIdx.x * 16 + r16;
  const float bet = beta[n];
#pragma unroll
  for (int mt = 0; mt < 3; ++mt) {
    const int mbase = wv * 48 + mt * 16 + q * 4;
#pragma unroll
    for (int r = 0; r < 4; ++r) {
      const int m = mbase + r;
      float v = acc[mt][r];
      if (m == 128) v += bet;
      unsigned short h = f2bf(v);
      oh[m * ND + n] = h;
      ol[m * ND + n] = f2bf(v - bf2f(h));
    }
  }
}

// Last step (t=10): only n in [1920,2048) is ever read. 8 blocks. Writes
// S[e*128+d] = Q10[d, 1920+e] (fp32) and cvec[e] = Q10[128, 1920+e]+beta.
__global__ __launch_bounds__(192) void step_last(
    const unsigned short* __restrict__ Ahi, const unsigned short* __restrict__ Alo,
    const unsigned short* __restrict__ qh, const unsigned short* __restrict__ ql,
    const float* __restrict__ beta,
    float* __restrict__ S, float* __restrict__ cvec) {
  const int t = threadIdx.x;
  const int nb = blockIdx.x + 120;
  f32x4 acc[3];
  step_core(Ahi, Alo, qh, ql, nb, t, acc);

  const int wv = t >> 6, lane = t & 63;
  const int r16 = lane & 15, q = lane >> 4;
  const int n = nb * 16 + r16;
  const int e = n - 1920;
  const float bet = beta[n];
#pragma unroll
  for (int mt = 0; mt < 3; ++mt) {
    const int mbase = wv * 48 + mt * 16 + q * 4;
#pragma unroll
    for (int r = 0; r < 4; ++r) {
      const int m = mbase + r;
      float v = acc[mt][r];
      if (m < 128) S[e * 128 + m] = v;       // d = m
      else if (m == 128) cvec[e] = v + bet;
    }
  }
}

// ---------------------------------------------------------------------------
// Fused tail: 64 blocks x 256 thr; block b owns ic-chunk [b*8, b*8+8).
// Phase 1: T1[e][icl] = sum_d S[e,d]*Wpre[d, ic0+icl] into LDS (4 KB).
//          Block 0 also: g[e] = cvec[e] + S.bpre into LDS.
// Phase 2: Weff[o, ic0+icl] = sum_e Wpost[o,e]*T1[e][icl] -> split bf16.
//          Block 0 also: beff[o] = bpost[o] + Wpost.g.
// ---------------------------------------------------------------------------
__global__ __launch_bounds__(256) void tail_kernel(
    const float* __restrict__ S, const float* __restrict__ cvec,
    const float* __restrict__ Wpre, const float* __restrict__ bpre,
    const float* __restrict__ Wpost, const float* __restrict__ bpost,
    unsigned short* __restrict__ Whi, unsigned short* __restrict__ Wlo,
    float* __restrict__ beff) {
  __shared__ float Ts[128][8];
  __shared__ float gs[128];
  const int b = blockIdx.x, t = threadIdx.x;
  const int ic0 = b * 8;
#pragma unroll
  for (int rr = 0; rr < 4; ++rr) {
    int x = t + rr * 256;
    int e = x >> 3, icl = x & 7;
    float s = 0.f;
    for (int d = 0; d < 128; ++d) s += S[e * 128 + d] * Wpre[d * 512 + ic0 + icl];
    Ts[e][icl] = s;
  }
  if (b == 0 && t < 128) {
    float s = cvec[t];
    for (int d = 0; d < 128; ++d) s += S[t * 128 + d] * bpre[d];
    gs[t] = s;
  }
  __syncthreads();
#pragma unroll
  for (int rr = 0; rr < 16; ++rr) {
    int x = t + rr * 256;
    int o = x >> 3, icl = x & 7;
    float s = 0.f;
    for (int e = 0; e < 128; ++e) s += Wpost[o * 128 + e] * Ts[e][icl];
    unsigned short h = f2bf(s);
    Whi[o * 512 + ic0 + icl] = h;
    Wlo[o * 512 + ic0 + icl] = f2bf(s - bf2f(h));
  }
  if (b == 0) {
    for (int o = t; o < 512; o += 256) {
      float s = bpost[o];
      for (int e = 0; e < 128; ++e) s += Wpost[o * 128 + e] * gs[e];
      beff[o] = s;
    }
  }
}

// ---------------------------------------------------------------------------
// out[4096,512] = inp @ Weff^T + beff. M=4096,N=512,K=512, split bf16.
// ---------------------------------------------------------------------------
__global__ __launch_bounds__(256) void final_gemm(
    const unsigned short* __restrict__ Ihi, const unsigned short* __restrict__ Ilo,
    const unsigned short* __restrict__ Whi, const unsigned short* __restrict__ Wlo,
    const float* __restrict__ beff, float* __restrict__ out) {
  __shared__ __align__(16) unsigned short Is_hi[64][40], Is_lo[64][40];
  __shared__ __align__(16) unsigned short Ws_hi[128][40], Ws_lo[128][40];
  const int t = threadIdx.x;
  const int mb = blockIdx.x, nb = blockIdx.y;
  const int w = t >> 6, lane = t & 63;
  const int r16 = lane & 15, q = lane >> 4;

  f32x4 acc[4][2];
#pragma unroll
  for (int x = 0; x < 4; ++x)
#pragma unroll
    for (int y = 0; y < 2; ++y) acc[x][y] = (f32x4){0.f, 0.f, 0.f, 0.f};

  for (int kc = 0; kc < 16; ++kc) {
    const int k0 = kc * 32;
#pragma unroll
    for (int rpt = 0; rpt < 6; ++rpt) {
      int slot = t + rpt * 256;
      if (slot < 512) {
        int arr = slot >> 8, s = slot & 255;
        int row = s >> 2, off = (s & 3) * 8;
        const unsigned short* src = arr ? Ilo : Ihi;
        unsigned short* dst = arr ? &Is_lo[row][off] : &Is_hi[row][off];
        *(uint4*)dst = *(const uint4*)(src + (mb * 64 + row) * 512 + k0 + off);
      } else {
        int s = slot - 512;
        int arr = s >> 9, s2 = s & 511;
        int row = s2 >> 2, off = (s2 & 3) * 8;
        const unsigned short* src = arr ? Wlo : Whi;
        unsigned short* dst = arr ? &Ws_lo[row][off] : &Ws_hi[row][off];
        *(uint4*)dst = *(const uint4*)(src + (nb * 128 + row) * 512 + k0 + off);
      }
    }
    __syncthreads();

    bf16x8 bh0 = __builtin_bit_cast(bf16x8, *(const uint4*)&Ws_hi[w * 32 + r16][q * 8]);
    bf16x8 bl0 = __builtin_bit_cast(bf16x8, *(const uint4*)&Ws_lo[w * 32 + r16][q * 8]);
    bf16x8 bh1 = __builtin_bit_cast(bf16x8, *(const uint4*)&Ws_hi[w * 32 + 16 + r16][q * 8]);
    bf16x8 bl1 = __builtin_bit_cast(bf16x8, *(const uint4*)&Ws_lo[w * 32 + 16 + r16][q * 8]);
#pragma unroll
    for (int mt = 0; mt < 4; ++mt) {
      bf16x8 ah = __builtin_bit_cast(bf16x8, *(const uint4*)&Is_hi[mt * 16 + r16][q * 8]);
      bf16x8 al = __builtin_bit_cast(bf16x8, *(const uint4*)&Is_lo[mt * 16 + r16][q * 8]);
      acc[mt][0] = mfma16(ah, bh0, acc[mt][0]);
      acc[mt][0] = mfma16(al, bh0, acc[mt][0]);
      acc[mt][0] = mfma16(ah, bl0, acc[mt][0]);
      acc[mt][1] = mfma16(ah, bh1, acc[mt][1]);
      acc[mt][1] = mfma16(al, bh1, acc[mt][1]);
      acc[mt][1] = mfma16(ah, bl1, acc[mt][1]);
    }
    __syncthreads();
  }

#pragma unroll
  for (int mt = 0; mt < 4; ++mt)
#pragma unroll
    for (int nt = 0; nt < 2; ++nt) {
      int n = nb * 128 + w * 32 + nt * 16 + r16;
      float bv = beff[n];
#pragma unroll
      for (int r = 0; r < 4; ++r) {
        int m = mb * 64 + mt * 16 + q * 4 + r;
        out[m * 512 + n] = acc[mt][nt][r] + bv;
      }
    }
}

extern "C" void kernel_launch(void* const* d_in, const int* in_sizes, int n_in,
                              void* d_out, int out_size, void* d_ws, size_t ws_size,
                              hipStream_t stream) {
  const float* inp   = (const float*)d_in[0];
  const float* Wpre  = (const float*)d_in[1];
  const float* bpre  = (const float*)d_in[2];
  const float* W     = (const float*)d_in[3];
  const float* bl    = (const float*)d_in[4];
  const float* life  = (const float*)d_in[5];
  const float* Wpost = (const float*)d_in[6];
  const float* bpost = (const float*)d_in[7];
  float* out = (float*)d_out;

  char* p = (char*)d_ws;
  auto alloc = [&](size_t bytes) {
    char* r = p;
    p += (bytes + 255) & ~(size_t)255;
    return r;
  };
  unsigned short* Ahi  = (unsigned short*)alloc((size_t)ND * ND * 2);
  unsigned short* Alo  = (unsigned short*)alloc((size_t)ND * ND * 2);
  unsigned short* QAhi = (unsigned short*)alloc((size_t)MT * ND * 2);
  unsigned short* QAlo = (unsigned short*)alloc((size_t)MT * ND * 2);
  unsigned short* QBhi = (unsigned short*)alloc((size_t)MT * ND * 2);
  unsigned short* QBlo = (unsigned short*)alloc((size_t)MT * ND * 2);
  float* beta = (float*)alloc(ND * 4);
  float* S    = (float*)alloc(128 * 128 * 4);
  float* cvec = (float*)alloc(128 * 4);
  unsigned short* Whi = (unsigned short*)alloc(512 * 512 * 2);
  unsigned short* Wlo = (unsigned short*)alloc(512 * 512 * 2);
  float* beff = (float*)alloc(512 * 4);
  unsigned short* Ihi = (unsigned short*)alloc((size_t)4096 * 512 * 2);
  unsigned short* Ilo = (unsigned short*)alloc((size_t)4096 * 512 * 2);

  prep_kernel<<<3136, 256, 0, stream>>>(W, life, inp, bl, Ahi, Alo, Ihi, Ilo,
                                        QAhi, QAlo, beta);

  // steps t=2..9 (8 full steps), ping-pong QA <-> QB; result lands in QA
  const unsigned short *qh = QAhi, *ql = QAlo;
  unsigned short *oh = QBhi, *ol = QBlo;
  for (int i = 0; i < 8; ++i) {
    step_full<<<128, 192, 0, stream>>>(Ahi, Alo, qh, ql, beta, oh, ol);
    const unsigned short* th = qh; qh = oh; oh = (unsigned short*)th;
    const unsigned short* tl = ql; ql = ol; ol = (unsigned short*)tl;
  }
  // step t=10 restricted to n in [1920,2048): writes S + cvec
  step_last<<<8, 192, 0, stream>>>(Ahi, Alo, qh, ql, beta, S, cvec);

  tail_kernel<<<64, 256, 0, stream>>>(S, cvec, Wpre, bpre, Wpost, bpost,
                                      Whi, Wlo, beff);

  final_gemm<<<dim3(64, 4), 256, 0, stream>>>(Ihi, Ilo, Whi, Wlo, beff, out);
}

// Round 6
// 390.105 us; speedup vs baseline: 2.3569x; 1.5175x over previous
//
#include <hip/hip_runtime.h>

// ---------------------------------------------------------------------------
// Algebraic collapse: the scan is linear & batch-independent.
//   m_{t+1} = A m_t + beta,  A[(j,e),(i,d)] = gate[i,j]*W[i,j,e,d]
//   out = inp @ Weff^T + beff,  Weff = Wpost * S * Wpre,
//   S = (A^10)[block15, block0],  c = (sum_{k<10} A^k beta)[block15]
// QT [144 x 2048] iterate in split-bf16 (hi+lo), fp32 MFMA accumulate.
// Round 6: occupancy fix. Step = grid(128 nb x 3 mg) x 256 thr (4 waves),
// K split across the block's waves (512 each), LDS cross-wave reduce +
// fused beta/split epilogue -> 1536 waves (6/CU) vs R5's 384, no global
// partials, no extra dispatches. Tail split into two wide coalesced kernels.
// ---------------------------------------------------------------------------

typedef __bf16 bf16x8 __attribute__((ext_vector_type(8)));
typedef float f32x4 __attribute__((ext_vector_type(4)));

__device__ __forceinline__ unsigned short f2bf(float x) {
  unsigned int u = __float_as_uint(x);
  u += 0x7FFFu + ((u >> 16) & 1u);   // round-to-nearest-even
  return (unsigned short)(u >> 16);
}
__device__ __forceinline__ float bf2f(unsigned short s) {
  return __uint_as_float(((unsigned int)s) << 16);
}
__device__ __forceinline__ bf16x8 ldg8(const unsigned short* p) {
  return __builtin_bit_cast(bf16x8, *(const uint4*)p);
}
__device__ __forceinline__ f32x4 mfma16(bf16x8 a, bf16x8 b, f32x4 c) {
  return __builtin_amdgcn_mfma_f32_16x16x32_bf16(a, b, c, 0, 0, 0);
}

#define ND 2048   // num*dim
#define MT 144    // iterate rows (129 used: 128 propagator + 1 bias; rest 0)

// ---------------------------------------------------------------------------
// prep: blocks 0..2047 build split-A; 2048..3071 split inp; 3072..3135 build
// Q1 (exact step t=1) directly from W + beta row. All independent.
// ---------------------------------------------------------------------------
__global__ __launch_bounds__(256) void prep_kernel(
    const float* __restrict__ W, const float* __restrict__ life,
    const float* __restrict__ inp, const float* __restrict__ bl,
    unsigned short* __restrict__ Ahi, unsigned short* __restrict__ Alo,
    unsigned short* __restrict__ Ihi, unsigned short* __restrict__ Ilo,
    unsigned short* __restrict__ Qhi, unsigned short* __restrict__ Qlo,
    float* __restrict__ beta) {
  const int b = blockIdx.x, t = threadIdx.x;
  if (b < 2048) {
    long base = ((long)b * 256 + t) * 8;
    int n = (int)(base >> 11), k = (int)(base & 2047);
    int j = n >> 7, e = n & 127, i = k >> 7, d0 = k & 127;
    float gv = life[i * 16 + j];
    float gate = gv > 0.f ? gv : 0.f;
    const float* src = W + ((i * 16 + j) * 16384 + e * 128 + d0);
    float4 a = *(const float4*)src, b4 = *(const float4*)(src + 4);
    float vals[8] = {a.x, a.y, a.z, a.w, b4.x, b4.y, b4.z, b4.w};
    union { unsigned short u[8]; uint4 v; } ph, pl;
#pragma unroll
    for (int x = 0; x < 8; ++x) {
      float v = gate * vals[x];
      unsigned short h = f2bf(v);
      ph.u[x] = h;
      pl.u[x] = f2bf(v - bf2f(h));
    }
    *(uint4*)(Ahi + base) = ph.v;
    *(uint4*)(Alo + base) = pl.v;
  } else if (b < 3072) {
    long base = ((long)(b - 2048) * 256 + t) * 8;
    float4 a = *(const float4*)(inp + base), b4 = *(const float4*)(inp + base + 4);
    float vals[8] = {a.x, a.y, a.z, a.w, b4.x, b4.y, b4.z, b4.w};
    union { unsigned short u[8]; uint4 v; } ph, pl;
#pragma unroll
    for (int x = 0; x < 8; ++x) {
      unsigned short h = f2bf(vals[x]);
      ph.u[x] = h;
      pl.u[x] = f2bf(vals[x] - bf2f(h));
    }
    *(uint4*)(Ihi + base) = ph.v;
    *(uint4*)(Ilo + base) = pl.v;
  } else {
    // Q1[c][n] = gate[0,j]*W[0,j,e,c] (exact t=1), c<128; row 128 = beta.
    const int nb = b - 3072;                 // n-range [nb*32, nb*32+32)
    {
      int n = nb * 32 + (t >> 3);
      int c0 = (t & 7) * 16;
      int j = n >> 7, e = n & 127;
      float gv = life[j];
      float gate = gv > 0.f ? gv : 0.f;
      const float* src = W + (j * 16384 + e * 128 + c0);
      float4 w0 = *(const float4*)src, w1 = *(const float4*)(src + 4);
      float4 w2 = *(const float4*)(src + 8), w3 = *(const float4*)(src + 12);
      float vals[16] = {w0.x, w0.y, w0.z, w0.w, w1.x, w1.y, w1.z, w1.w,
                        w2.x, w2.y, w2.z, w2.w, w3.x, w3.y, w3.z, w3.w};
#pragma unroll
      for (int x = 0; x < 16; ++x) {
        float v = gate * vals[x];
        unsigned short h = f2bf(v);
        Qhi[(c0 + x) * ND + n] = h;
        Qlo[(c0 + x) * ND + n] = f2bf(v - bf2f(h));
      }
    }
    if (t < 32) {
      int n = nb * 32 + t;
      int j = n >> 7, e = n & 127;
      float s = 0.f;
#pragma unroll
      for (int i = 0; i < 16; ++i) {
        float gv = life[i * 16 + j];
        float g = gv > 0.f ? gv : 0.f;
        s += g * bl[(i * 16 + j) * 128 + e];
      }
      beta[n] = s;
      unsigned short h = f2bf(s);
      Qhi[128 * ND + n] = h;
      Qlo[128 * ND + n] = f2bf(s - bf2f(h));
    }
    for (int idx = t; idx < 480; idx += 256) {
      int r = 129 + (idx >> 5), n = nb * 32 + (idx & 31);
      Qhi[r * ND + n] = 0;
      Qlo[r * ND + n] = 0;
    }
  }
}

// ---------------------------------------------------------------------------
// Full step: grid (128 nb, 3 mg) x 256 thr. Wave wv owns K-chunk
// [wv*512, +512), m-rows [mg*48, +48) (3 m-tiles), n-tile nb (16 cols).
// Cross-wave K-reduce via LDS; epilogue fuses +beta (row 128) and the
// split-bf16 write of Q'.
// ---------------------------------------------------------------------------
__global__ __launch_bounds__(256) void step_full(
    const unsigned short* __restrict__ Ahi, const unsigned short* __restrict__ Alo,
    const unsigned short* __restrict__ qh, const unsigned short* __restrict__ ql,
    const float* __restrict__ beta,
    unsigned short* __restrict__ oh, unsigned short* __restrict__ ol) {
  __shared__ float red[4][3][256];   // [wave][m-tile][m_local*16 + n_local]
  const int t = threadIdx.x;
  const int wv = t >> 6, lane = t & 63;
  const int r16 = lane & 15, q = lane >> 4;
  const int nb = blockIdx.x, mg = blockIdx.y;
  const int n0 = nb * 16;
  const int kbase = wv * 512 + q * 8;

  const unsigned short* pBh = Ahi + (n0 + r16) * ND + kbase;
  const unsigned short* pBl = Alo + (n0 + r16) * ND + kbase;
  const int m0 = mg * 48 + r16;
  const unsigned short* pAh = qh + m0 * ND + kbase;
  const unsigned short* pAl = ql + m0 * ND + kbase;

  f32x4 acc[3];
  acc[0] = acc[1] = acc[2] = (f32x4){0.f, 0.f, 0.f, 0.f};

#pragma unroll 4
  for (int it = 0; it < 16; ++it) {
    const int ko = it * 32;
    bf16x8 bh = ldg8(pBh + ko), bl = ldg8(pBl + ko);
    bf16x8 a0h = ldg8(pAh + ko), a0l = ldg8(pAl + ko);
    bf16x8 a1h = ldg8(pAh + 16 * ND + ko), a1l = ldg8(pAl + 16 * ND + ko);
    bf16x8 a2h = ldg8(pAh + 32 * ND + ko), a2l = ldg8(pAl + 32 * ND + ko);

    acc[0] = mfma16(a0h, bh, acc[0]);
    acc[0] = mfma16(a0l, bh, acc[0]);
    acc[0] = mfma16(a0h, bl, acc[0]);
    acc[1] = mfma16(a1h, bh, acc[1]);
    acc[1] = mfma16(a1l, bh, acc[1]);
    acc[1] = mfma16(a1h, bl, acc[1]);
    acc[2] = mfma16(a2h, bh, acc[2]);
    acc[2] = mfma16(a2l, bh, acc[2]);
    acc[2] = mfma16(a2h, bl, acc[2]);
  }

#pragma unroll
  for (int mt = 0; mt < 3; ++mt)
#pragma unroll
    for (int r = 0; r < 4; ++r)
      red[wv][mt][(q * 4 + r) * 16 + r16] = acc[mt][r];
  __syncthreads();

#pragma unroll
  for (int rr = 0; rr < 3; ++rr) {
    const int x = t + rr * 256;
    const int mt = x >> 8, ml = (x >> 4) & 15, nl = x & 15;
    const int li = ml * 16 + nl;
    float v = red[0][mt][li] + red[1][mt][li] + red[2][mt][li] + red[3][mt][li];
    const int m = mg * 48 + mt * 16 + ml;
    const int n = n0 + nl;
    if (m == 128) v += beta[n];
    unsigned short h = f2bf(v);
    oh[m * ND + n] = h;
    ol[m * ND + n] = f2bf(v - bf2f(h));
  }
}

// ---------------------------------------------------------------------------
// Last step (t=10): only n in [1920,2048) is read downstream. grid (8 nb,
// 9 mt) x 256 thr; wave wv owns K-chunk of 512, ONE m-tile. LDS reduce,
// then write S[e,d] fp32 (m<128) / cvec[e]=v+beta (m==128) directly.
// ---------------------------------------------------------------------------
__global__ __launch_bounds__(256) void step_last(
    const unsigned short* __restrict__ Ahi, const unsigned short* __restrict__ Alo,
    const unsigned short* __restrict__ qh, const unsigned short* __restrict__ ql,
    const float* __restrict__ beta,
    float* __restrict__ S, float* __restrict__ cvec) {
  __shared__ float red[4][256];
  const int t = threadIdx.x;
  const int wv = t >> 6, lane = t & 63;
  const int r16 = lane & 15, q = lane >> 4;
  const int nb = blockIdx.x + 120, mt = blockIdx.y;
  const int n0 = nb * 16;
  const int kbase = wv * 512 + q * 8;

  const unsigned short* pBh = Ahi + (n0 + r16) * ND + kbase;
  const unsigned short* pBl = Alo + (n0 + r16) * ND + kbase;
  const int m0 = mt * 16 + r16;
  const unsigned short* pAh = qh + m0 * ND + kbase;
  const unsigned short* pAl = ql + m0 * ND + kbase;

  f32x4 acc = (f32x4){0.f, 0.f, 0.f, 0.f};
#pragma unroll 4
  for (int it = 0; it < 16; ++it) {
    const int ko = it * 32;
    bf16x8 bh = ldg8(pBh + ko), bl = ldg8(pBl + ko);
    bf16x8 ah = ldg8(pAh + ko), al = ldg8(pAl + ko);
    acc = mfma16(ah, bh, acc);
    acc = mfma16(al, bh, acc);
    acc = mfma16(ah, bl, acc);
  }
#pragma unroll
  for (int r = 0; r < 4; ++r)
    red[wv][(q * 4 + r) * 16 + r16] = acc[r];
  __syncthreads();

  {
    const int ml = t >> 4, nl = t & 15;
    const int li = ml * 16 + nl;
    float v = red[0][li] + red[1][li] + red[2][li] + red[3][li];
    const int m = mt * 16 + ml;
    const int n = n0 + nl;
    const int e = n - 1920;
    if (m < 128) S[e * 128 + m] = v;                 // d = m
    else if (m == 128) cvec[e] = v + beta[n];
  }
}

// ---------------------------------------------------------------------------
// tail1: blocks 0..127 -> T1 row e (512 cols, coalesced Wpre reads);
//        block 128 -> g[e] = cvec[e] + S[e,:].bpre
// ---------------------------------------------------------------------------
__global__ __launch_bounds__(256) void tail1(
    const float* __restrict__ S, const float* __restrict__ cvec,
    const float* __restrict__ Wpre, const float* __restrict__ bpre,
    float* __restrict__ T1, float* __restrict__ g) {
  const int b = blockIdx.x, t = threadIdx.x;
  if (b < 128) {
    float s0 = 0.f, s1 = 0.f;
    for (int d = 0; d < 128; ++d) {
      const float sv = S[b * 128 + d];
      s0 += sv * Wpre[d * 512 + t];
      s1 += sv * Wpre[d * 512 + t + 256];
    }
    T1[b * 512 + t] = s0;
    T1[b * 512 + t + 256] = s1;
  } else if (t < 128) {
    float s = cvec[t];
    for (int d = 0; d < 128; ++d) s += S[t * 128 + d] * bpre[d];
    g[t] = s;
  }
}

// ---------------------------------------------------------------------------
// tail2: blocks 0..511 -> Weff row o (split bf16, coalesced T1 reads);
//        block 512 -> beff.
// ---------------------------------------------------------------------------
__global__ __launch_bounds__(256) void tail2(
    const float* __restrict__ T1, const float* __restrict__ g,
    const float* __restrict__ Wpost, const float* __restrict__ bpost,
    unsigned short* __restrict__ Whi, unsigned short* __restrict__ Wlo,
    float* __restrict__ beff) {
  const int b = blockIdx.x, t = threadIdx.x;
  if (b < 512) {
    float s0 = 0.f, s1 = 0.f;
    for (int e = 0; e < 128; ++e) {
      const float w = Wpost[b * 128 + e];
      s0 += w * T1[e * 512 + t];
      s1 += w * T1[e * 512 + t + 256];
    }
    unsigned short h0 = f2bf(s0), h1 = f2bf(s1);
    Whi[b * 512 + t] = h0;
    Wlo[b * 512 + t] = f2bf(s0 - bf2f(h0));
    Whi[b * 512 + t + 256] = h1;
    Wlo[b * 512 + t + 256] = f2bf(s1 - bf2f(h1));
  } else {
#pragma unroll
    for (int rr = 0; rr < 2; ++rr) {
      const int o = t + rr * 256;
      float s = bpost[o];
      for (int e = 0; e < 128; ++e) s += Wpost[o * 128 + e] * g[e];
      beff[o] = s;
    }
  }
}

// ---------------------------------------------------------------------------
// out[4096,512] = inp @ Weff^T + beff. M=4096,N=512,K=512, split bf16.
// ---------------------------------------------------------------------------
__global__ __launch_bounds__(256) void final_gemm(
    const unsigned short* __restrict__ Ihi, const unsigned short* __restrict__ Ilo,
    const unsigned short* __restrict__ Whi, const unsigned short* __restrict__ Wlo,
    const float* __restrict__ beff, float* __restrict__ out) {
  __shared__ __align__(16) unsigned short Is_hi[64][40], Is_lo[64][40];
  __shared__ __align__(16) unsigned short Ws_hi[128][40], Ws_lo[128][40];
  const int t = threadIdx.x;
  const int mb = blockIdx.x, nb = blockIdx.y;
  const int w = t >> 6, lane = t & 63;
  const int r16 = lane & 15, q = lane >> 4;

  f32x4 acc[4][2];
#pragma unroll
  for (int x = 0; x < 4; ++x)
#pragma unroll
    for (int y = 0; y < 2; ++y) acc[x][y] = (f32x4){0.f, 0.f, 0.f, 0.f};

  for (int kc = 0; kc < 16; ++kc) {
    const int k0 = kc * 32;
#pragma unroll
    for (int rpt = 0; rpt < 6; ++rpt) {
      int slot = t + rpt * 256;
      if (slot < 512) {
        int arr = slot >> 8, s = slot & 255;
        int row = s >> 2, off = (s & 3) * 8;
        const unsigned short* src = arr ? Ilo : Ihi;
        unsigned short* dst = arr ? &Is_lo[row][off] : &Is_hi[row][off];
        *(uint4*)dst = *(const uint4*)(src + (mb * 64 + row) * 512 + k0 + off);
      } else {
        int s = slot - 512;
        int arr = s >> 9, s2 = s & 511;
        int row = s2 >> 2, off = (s2 & 3) * 8;
        const unsigned short* src = arr ? Wlo : Whi;
        unsigned short* dst = arr ? &Ws_lo[row][off] : &Ws_hi[row][off];
        *(uint4*)dst = *(const uint4*)(src + (nb * 128 + row) * 512 + k0 + off);
      }
    }
    __syncthreads();

    bf16x8 bh0 = __builtin_bit_cast(bf16x8, *(const uint4*)&Ws_hi[w * 32 + r16][q * 8]);
    bf16x8 bl0 = __builtin_bit_cast(bf16x8, *(const uint4*)&Ws_lo[w * 32 + r16][q * 8]);
    bf16x8 bh1 = __builtin_bit_cast(bf16x8, *(const uint4*)&Ws_hi[w * 32 + 16 + r16][q * 8]);
    bf16x8 bl1 = __builtin_bit_cast(bf16x8, *(const uint4*)&Ws_lo[w * 32 + 16 + r16][q * 8]);
#pragma unroll
    for (int mt = 0; mt < 4; ++mt) {
      bf16x8 ah = __builtin_bit_cast(bf16x8, *(const uint4*)&Is_hi[mt * 16 + r16][q * 8]);
      bf16x8 al = __builtin_bit_cast(bf16x8, *(const uint4*)&Is_lo[mt * 16 + r16][q * 8]);
      acc[mt][0] = mfma16(ah, bh0, acc[mt][0]);
      acc[mt][0] = mfma16(al, bh0, acc[mt][0]);
      acc[mt][0] = mfma16(ah, bl0, acc[mt][0]);
      acc[mt][1] = mfma16(ah, bh1, acc[mt][1]);
      acc[mt][1] = mfma16(al, bh1, acc[mt][1]);
      acc[mt][1] = mfma16(ah, bl1, acc[mt][1]);
    }
    __syncthreads();
  }

#pragma unroll
  for (int mt = 0; mt < 4; ++mt)
#pragma unroll
    for (int nt = 0; nt < 2; ++nt) {
      int n = nb * 128 + w * 32 + nt * 16 + r16;
      float bv = beff[n];
#pragma unroll
      for (int r = 0; r < 4; ++r) {
        int m = mb * 64 + mt * 16 + q * 4 + r;
        out[m * 512 + n] = acc[mt][nt][r] + bv;
      }
    }
}

extern "C" void kernel_launch(void* const* d_in, const int* in_sizes, int n_in,
                              void* d_out, int out_size, void* d_ws, size_t ws_size,
                              hipStream_t stream) {
  const float* inp   = (const float*)d_in[0];
  const float* Wpre  = (const float*)d_in[1];
  const float* bpre  = (const float*)d_in[2];
  const float* W     = (const float*)d_in[3];
  const float* bl    = (const float*)d_in[4];
  const float* life  = (const float*)d_in[5];
  const float* Wpost = (const float*)d_in[6];
  const float* bpost = (const float*)d_in[7];
  float* out = (float*)d_out;

  char* p = (char*)d_ws;
  auto alloc = [&](size_t bytes) {
    char* r = p;
    p += (bytes + 255) & ~(size_t)255;
    return r;
  };
  unsigned short* Ahi  = (unsigned short*)alloc((size_t)ND * ND * 2);
  unsigned short* Alo  = (unsigned short*)alloc((size_t)ND * ND * 2);
  unsigned short* QAhi = (unsigned short*)alloc((size_t)MT * ND * 2);
  unsigned short* QAlo = (unsigned short*)alloc((size_t)MT * ND * 2);
  unsigned short* QBhi = (unsigned short*)alloc((size_t)MT * ND * 2);
  unsigned short* QBlo = (unsigned short*)alloc((size_t)MT * ND * 2);
  float* beta = (float*)alloc(ND * 4);
  float* S    = (float*)alloc(128 * 128 * 4);
  float* cvec = (float*)alloc(128 * 4);
  float* T1   = (float*)alloc(128 * 512 * 4);
  float* g    = (float*)alloc(128 * 4);
  unsigned short* Whi = (unsigned short*)alloc(512 * 512 * 2);
  unsigned short* Wlo = (unsigned short*)alloc(512 * 512 * 2);
  float* beff = (float*)alloc(512 * 4);
  unsigned short* Ihi = (unsigned short*)alloc((size_t)4096 * 512 * 2);
  unsigned short* Ilo = (unsigned short*)alloc((size_t)4096 * 512 * 2);

  prep_kernel<<<3136, 256, 0, stream>>>(W, life, inp, bl, Ahi, Alo, Ihi, Ilo,
                                        QAhi, QAlo, beta);

  // steps t=2..9 (8 full steps), ping-pong QA <-> QB; result lands in QA
  const unsigned short *qh = QAhi, *ql = QAlo;
  unsigned short *oh = QBhi, *ol = QBlo;
  for (int i = 0; i < 8; ++i) {
    step_full<<<dim3(128, 3), 256, 0, stream>>>(Ahi, Alo, qh, ql, beta, oh, ol);
    const unsigned short* th = qh; qh = oh; oh = (unsigned short*)th;
    const unsigned short* tl = ql; ql = ol; ol = (unsigned short*)tl;
  }
  // step t=10 restricted to n in [1920,2048): writes S + cvec directly
  step_last<<<dim3(8, 9), 256, 0, stream>>>(Ahi, Alo, qh, ql, beta, S, cvec);

  tail1<<<129, 256, 0, stream>>>(S, cvec, Wpre, bpre, T1, g);
  tail2<<<513, 256, 0, stream>>>(T1, g, Wpost, bpost, Whi, Wlo, beff);

  final_gemm<<<dim3(64, 4), 256, 0, stream>>>(Ihi, Ilo, Whi, Wlo, beff, out);
}